// Round 8
// baseline (347.619 us; speedup 1.0000x reference)
//
#include <hip/hip_runtime.h>
#include <math.h>

#define H  64
#define D  128
#define G  192
#define BB 256
#define TT 1024
#define CT 16
#define NC (TT / CT)
#define GP2 196      // padded xgbuf row stride (floats)
#define NT 256
#define LOG2E 1.4426950408889634f

typedef __attribute__((ext_vector_type(8))) short bf16x8;
typedef __attribute__((ext_vector_type(4))) float f32x4;
typedef __attribute__((ext_vector_type(2))) __fp16 fp16x2;

static __device__ __forceinline__ unsigned cvt_pk_bf16(float a, float b) {
    unsigned r;
    asm volatile("v_cvt_pk_bf16_f32 %0, %1, %2" : "=v"(r) : "v"(a), "v"(b));
    return r;
}
static __device__ __forceinline__ float lo16_f(unsigned u) { union {unsigned u; float f;} v; v.u = u << 16;         return v.f; }
static __device__ __forceinline__ float hi16_f(unsigned u) { union {unsigned u; float f;} v; v.u = u & 0xffff0000u; return v.f; }

static __device__ __forceinline__ void split8(const float w[8], bf16x8* hi, bf16x8* lo) {
    union { bf16x8 v; unsigned u[4]; } Hu, Lu;
    #pragma unroll
    for (int p = 0; p < 4; ++p) {
        const unsigned hp = cvt_pk_bf16(w[2*p], w[2*p+1]);
        Hu.u[p] = hp;
        Lu.u[p] = cvt_pk_bf16(w[2*p] - lo16_f(hp), w[2*p+1] - hi16_f(hp));
    }
    *hi = Hu.v; *lo = Lu.v;
}
static __device__ __forceinline__ bf16x8 pack8(const float w[8]) {
    union { bf16x8 v; unsigned u[4]; } P;
    #pragma unroll
    for (int p = 0; p < 4; ++p) P.u[p] = cvt_pk_bf16(w[2*p], w[2*p+1]);
    return P.v;
}
static __device__ __forceinline__ unsigned pkrtz_u32(float a, float b) {
    fp16x2 p = __builtin_amdgcn_cvt_pkrtz(a, b);
    return __builtin_bit_cast(unsigned, p);
}
// f32 += dot2(f16x2 w, f16x2 h-broadcast-from-SGPR)
static __device__ __forceinline__ float dot2f16(unsigned w, unsigned hp, float acc) {
    float r;
    asm("v_dot2_f32_f16 %0, %1, %2, %3" : "=v"(r) : "v"(w), "s"(hp), "v"(acc));
    return r;
}

// One block per batch row. Wave 0 = recurrence (register-resident, dot2-based).
// Waves 1..3 = x_gates producers (one gate-kind each), LDS double buffer.
__global__ __launch_bounds__(NT, 1) void gru_fused(
    const float* __restrict__ x,      // (B,T,D)
    const float* __restrict__ W_ih,   // (G,D)
    const float* __restrict__ b_ih,   // (G)
    const float* __restrict__ W_hh,   // (G,H)
    const float* __restrict__ b_hh,   // (G)
    const float* __restrict__ W1,     // (H,H)
    const float* __restrict__ b1,     // (H)
    const float* __restrict__ W2,     // (2,H)
    const float* __restrict__ b2,     // (2)
    float* __restrict__ out)          // (B,2)
{
    __shared__ float xgbuf[2][CT][GP2];   // ~25 KB scaled x_gates (f32), double buffered
    __shared__ float hsf[H];              // final h f32 for the head

    const int b    = blockIdx.x;
    const int tid  = threadIdx.x;
    const int wave = tid >> 6;
    const int lane = tid & 63;
    const int col  = lane & 15;
    const int kg   = lane >> 4;

    if (wave == 0) {
        // ================= CONSUMER: register-only recurrence =================
        // Lane l owns gate rows l (r), 64+l (z), 128+l (n) of W_hh', packed f16 pairs.
        unsigned wr[32], wz[32], wn[32];
        {
            const float2* pr = (const float2*)(W_hh + (size_t)lane * H);
            const float2* pz = (const float2*)(W_hh + (size_t)(64 + lane) * H);
            const float2* pn = (const float2*)(W_hh + (size_t)(128 + lane) * H);
            const float SR = -LOG2E, SN = -2.0f * LOG2E;
            #pragma unroll
            for (int i = 0; i < 32; ++i) {
                const float2 a = pr[i]; wr[i] = pkrtz_u32(a.x * SR, a.y * SR);
                const float2 c = pz[i]; wz[i] = pkrtz_u32(c.x * SR, c.y * SR);
                const float2 e = pn[i]; wn[i] = pkrtz_u32(e.x * SN, e.y * SN);
            }
        }
        const float bnp = -2.0f * LOG2E * b_hh[2 * H + lane];

        float h = 0.0f;
        __syncthreads();                      // chunk 0 produced

        for (int c = 0; c < NC; ++c) {
            const float* xgc = &xgbuf[c & 1][0][0];
            #pragma unroll 1
            for (int s = 0; s < CT; ++s) {
                const float xr = xgc[s * GP2 + lane];
                const float xz = xgc[s * GP2 + 64 + lane];
                const float xn = xgc[s * GP2 + 128 + lane];

                // pack h pair (h[2i],h[2i+1]) present on both lanes of each pair
                const int   hb  = __builtin_bit_cast(int, h);
                const int   nbi = __builtin_amdgcn_mov_dpp(hb, 0xB1, 0xf, 0xf, true); // quad swap
                const float nb  = __builtin_bit_cast(float, nbi);
                const float plo = (lane & 1) ? nb : h;
                const float phi = (lane & 1) ? h : nb;
                const unsigned pk = pkrtz_u32(plo, phi);

                unsigned hp[32];
                #pragma unroll
                for (int i = 0; i < 32; ++i)
                    hp[i] = (unsigned)__builtin_amdgcn_readlane((int)pk, 2 * i);

                float a0 = 0.f, a1 = 0.f, b0 = 0.f, b1_ = 0.f, c0 = 0.f, c1 = 0.f;
                #pragma unroll
                for (int i = 0; i < 16; ++i) {
                    a0  = dot2f16(wr[i],      hp[i],      a0);
                    b0  = dot2f16(wz[i],      hp[i],      b0);
                    c0  = dot2f16(wn[i],      hp[i],      c0);
                    a1  = dot2f16(wr[16 + i], hp[16 + i], a1);
                    b1_ = dot2f16(wz[16 + i], hp[16 + i], b1_);
                    c1  = dot2f16(wn[16 + i], hp[16 + i], c1);
                }

                const float r  = __builtin_amdgcn_rcpf(1.0f + __builtin_amdgcn_exp2f((a0 + a1) + xr));
                const float z  = __builtin_amdgcn_rcpf(1.0f + __builtin_amdgcn_exp2f((b0 + b1_) + xz));
                const float y  = fmaf(r, (c0 + c1) + bnp, xn);
                const float nn = fmaf(2.0f, __builtin_amdgcn_rcpf(1.0f + __builtin_amdgcn_exp2f(y)), -1.0f);
                h = fmaf(z, h - nn, nn);
            }
            __syncthreads();
        }

        // ================= head (wave 0 only) =================
        hsf[lane] = h;
        asm volatile("" ::: "memory");
        float a = b1[lane];
        const float4* w1r = (const float4*)(W1 + (size_t)lane * H);
        #pragma unroll
        for (int q = 0; q < H / 4; ++q) {
            const float4 hv = ((const float4*)hsf)[q];
            const float4 wv = w1r[q];
            a += hv.x * wv.x + hv.y * wv.y + hv.z * wv.z + hv.w * wv.w;
        }
        float p0 = a * W2[lane];
        float p1 = a * W2[H + lane];
        #pragma unroll
        for (int o = 32; o; o >>= 1) {
            p0 += __shfl_xor(p0, o, 64);
            p1 += __shfl_xor(p1, o, 64);
        }
        if (lane == 0) {
            const float l0 = p0 + b2[0], l1 = p1 + b2[1];
            const float m   = fmaxf(l0, l1);
            const float lse = m + logf(expf(l0 - m) + expf(l1 - m));
            out[b * 2 + 0] = l0 - lse;
            out[b * 2 + 1] = l1 - lse;
        }
    } else {
        // ================= PRODUCERS: one gate-kind per wave =================
        const int   kd = wave - 1;                       // 0=r 1=z 2=n
        const float sc = (kd == 2) ? -2.0f * LOG2E : -LOG2E;

        // A-role W_ih' fragments (hi/lo): lane holds W_ih'[kd*64 + T*16 + col][kt*32 + kg*8 ..]
        bf16x8 Wh[4][4], Wl[4][4];
        f32x4  biasv[4];
        #pragma unroll
        for (int T = 0; T < 4; ++T) {
            #pragma unroll
            for (int kt = 0; kt < 4; ++kt) {
                const float* wp = W_ih + (size_t)(kd * 64 + T * 16 + col) * D + kt * 32 + kg * 8;
                const float4 a = *(const float4*)wp;
                const float4 c2 = *(const float4*)(wp + 4);
                const float w8[8] = {a.x*sc, a.y*sc, a.z*sc, a.w*sc, c2.x*sc, c2.y*sc, c2.z*sc, c2.w*sc};
                split8(w8, &Wh[T][kt], &Wl[T][kt]);
            }
            const int g0 = kd * 64 + T * 16 + kg * 4;
            const float4 bi = *(const float4*)(b_ih + g0);
            f32x4 bv = (f32x4){bi.x, bi.y, bi.z, bi.w};
            if (kd < 2) {
                const float4 bh = *(const float4*)(b_hh + g0);
                bv += (f32x4){bh.x, bh.y, bh.z, bh.w};
            }
            biasv[T] = bv * sc;
        }

        const float* xb = x + (size_t)b * TT * D;

        auto produce = [&](int cc, int buf) {
            // B-fragments: x rows for 16 timesteps (col = t offset)
            bf16x8 Bx[4];
            const float* xp = xb + (size_t)(cc * CT + col) * D;
            #pragma unroll
            for (int kt = 0; kt < 4; ++kt) {
                const float4 a = *(const float4*)(xp + kt * 32 + kg * 8);
                const float4 c2 = *(const float4*)(xp + kt * 32 + kg * 8 + 4);
                const float w8[8] = {a.x, a.y, a.z, a.w, c2.x, c2.y, c2.z, c2.w};
                Bx[kt] = pack8(w8);
            }
            #pragma unroll
            for (int T = 0; T < 4; ++T) {
                f32x4 acc = biasv[T];
                #pragma unroll
                for (int kt = 0; kt < 4; ++kt) {
                    acc = __builtin_amdgcn_mfma_f32_16x16x32_bf16(Wh[T][kt], Bx[kt], acc, 0, 0, 0);
                    acc = __builtin_amdgcn_mfma_f32_16x16x32_bf16(Wl[T][kt], Bx[kt], acc, 0, 0, 0);
                }
                // C: row = gate offset 4*kg+r (within tile), col = t offset
                *(f32x4*)&xgbuf[buf][col][kd * 64 + T * 16 + 4 * kg] = acc;
            }
        };

        produce(0, 0);
        __syncthreads();
        for (int c = 0; c < NC; ++c) {
            if (c + 1 < NC) produce(c + 1, (c + 1) & 1);
            __syncthreads();
        }
    }
}

extern "C" void kernel_launch(void* const* d_in, const int* in_sizes, int n_in,
                              void* d_out, int out_size, void* d_ws, size_t ws_size,
                              hipStream_t stream) {
    const float* x    = (const float*)d_in[0];
    const float* W_ih = (const float*)d_in[1];
    const float* b_ih = (const float*)d_in[2];
    const float* W_hh = (const float*)d_in[3];
    const float* b_hh = (const float*)d_in[4];
    const float* W1   = (const float*)d_in[5];
    const float* b1   = (const float*)d_in[6];
    const float* W2   = (const float*)d_in[7];
    const float* b2   = (const float*)d_in[8];
    float* out = (float*)d_out;

    gru_fused<<<BB, NT, 0, stream>>>(x, W_ih, b_ih, W_hh, b_hh, W1, b1, W2, b2, out);
}